// Round 1
// baseline (181.638 us; speedup 1.0000x reference)
//
#include <hip/hip_runtime.h>
#include <stdint.h>

constexpr int LDIM = 4096;
constexpr int KTOP = 128;
constexpr int NT   = 256;
constexpr int PT   = LDIM / NT; // 16 elements per thread
#define EPSF 1e-8f

// order-preserving float->uint32 key: larger float => larger key
__device__ __forceinline__ uint32_t f2key(float f) {
    uint32_t u = __float_as_uint(f);
    return (u & 0x80000000u) ? ~u : (u | 0x80000000u);
}
__device__ __forceinline__ float key2f(uint32_t k) {
    uint32_t u = (k & 0x80000000u) ? (k & 0x7fffffffu) : ~k;
    return __uint_as_float(u);
}

__global__ __launch_bounds__(NT) void soft_thresh_kernel(
        const float* __restrict__ x, float* __restrict__ out) {
    __shared__ float s_row[LDIM];      // 16 KB row cache
    __shared__ float s_top[KTOP];      // unsorted top-k values (x - m)
    __shared__ float s_srt[KTOP];      // sorted descending
    __shared__ float s_cum[KTOP];      // serial cumsum
    __shared__ int   s_rp[NT];         // rank partials
    __shared__ int   s_red[NT / 64];   // cross-wave reduction
    __shared__ float s_wmax[NT / 64];
    __shared__ int   s_gat;
    __shared__ float s_tau;

    const int tid = threadIdx.x;
    const size_t base = (size_t)blockIdx.x * LDIM;
    const float* __restrict__ xr = x + base;
    float* __restrict__ orow = out + base;

    // ---- load row (coalesced float4), keep keys in registers, track max ----
    uint32_t key[PT];
    float vmax = -3.4e38f;
    #pragma unroll
    for (int i = 0; i < PT / 4; ++i) {
        const int idx = (i * NT + tid) * 4;
        const float4 v = *reinterpret_cast<const float4*>(xr + idx);
        *reinterpret_cast<float4*>(&s_row[idx]) = v;
        key[i * 4 + 0] = f2key(v.x);
        key[i * 4 + 1] = f2key(v.y);
        key[i * 4 + 2] = f2key(v.z);
        key[i * 4 + 3] = f2key(v.w);
        vmax = fmaxf(vmax, fmaxf(fmaxf(v.x, v.y), fmaxf(v.z, v.w)));
    }
    #pragma unroll
    for (int off = 32; off > 0; off >>= 1)
        vmax = fmaxf(vmax, __shfl_down(vmax, off));
    if ((tid & 63) == 0) s_wmax[tid >> 6] = vmax;
    __syncthreads();
    const float m = fmaxf(fmaxf(s_wmax[0], s_wmax[1]),
                          fmaxf(s_wmax[2], s_wmax[3]));

    // ---- binary bit-search for the 128th-largest key ----
    // invariant at end: count(key >= P) >= 128 > count(key > P)
    uint32_t P = 0;
    for (int bit = 31; bit >= 0; --bit) {
        const uint32_t cand = P | (1u << bit);
        int c = 0;
        #pragma unroll
        for (int i = 0; i < PT; ++i) c += (key[i] >= cand) ? 1 : 0;
        #pragma unroll
        for (int off = 32; off > 0; off >>= 1) c += __shfl_down(c, off);
        if ((tid & 63) == 0) s_red[tid >> 6] = c;
        __syncthreads();
        c = s_red[0] + s_red[1] + s_red[2] + s_red[3];
        if (c >= KTOP) P = cand;
        if (c == KTOP) break;          // exactly 128 keys >= P: done
        __syncthreads();               // protect s_red for next pass
    }

    // ---- gather strictly-greater, fill ties with threshold value ----
    if (tid == 0) s_gat = 0;
    __syncthreads();
    #pragma unroll
    for (int i = 0; i < PT; ++i) {
        if (key[i] > P) {
            const int slot = atomicAdd(&s_gat, 1);
            s_top[slot] = key2f(key[i]) - m;   // (x - m), fp32 like reference
        }
    }
    __syncthreads();
    const int c_gt = s_gat;                    // <= 128 by invariant
    const float pv = key2f(P) - m;
    for (int s2 = c_gt + tid; s2 < KTOP; s2 += NT) s_top[s2] = pv;
    __syncthreads();

    // ---- rank sort 128 values, j-loop split across 256 threads ----
    {
        const int vi = tid & (KTOP - 1);
        const int jb = (tid >> 7) * (KTOP / 2);
        const float v = s_top[vi];
        int r = 0;
        for (int j = 0; j < KTOP / 2; ++j) {
            const float w = s_top[jb + j];
            r += (w > v || (w == v && (jb + j) < vi)) ? 1 : 0;
        }
        s_rp[tid] = r;
    }
    __syncthreads();
    if (tid < KTOP) s_srt[s_rp[tid] + s_rp[tid + KTOP]] = s_top[tid];
    __syncthreads();

    // ---- serial cumsum (matches sequential fp32 association) ----
    if (tid == 0) {
        float c = 0.f;
        for (int j = 0; j < KTOP; ++j) { c += s_srt[j]; s_cum[j] = c; }
    }
    __syncthreads();

    // ---- support size + tau ----
    int sup = 0;
    if (tid < KTOP) {
        const float ratio = s_cum[tid] / (s_srt[tid] + EPSF);
        sup = ((float)(tid + 1) <= ratio) ? 1 : 0;
    }
    #pragma unroll
    for (int off = 32; off > 0; off >>= 1) sup += __shfl_down(sup, off);
    if ((tid & 63) == 0) s_red[tid >> 6] = sup;
    __syncthreads();
    if (tid == 0) {
        int support = s_red[0] + s_red[1] + s_red[2] + s_red[3];
        if (support < 1) support = 1;
        s_tau = s_cum[support - 1] / ((float)support + EPSF);
    }
    __syncthreads();
    const float tau = s_tau;

    // ---- output: max((x - m) - tau, 0), coalesced float4 stores ----
    #pragma unroll
    for (int i = 0; i < PT / 4; ++i) {
        const int idx = (i * NT + tid) * 4;
        const float4 v = *reinterpret_cast<const float4*>(&s_row[idx]);
        float4 o;
        o.x = fmaxf((v.x - m) - tau, 0.f);
        o.y = fmaxf((v.y - m) - tau, 0.f);
        o.z = fmaxf((v.z - m) - tau, 0.f);
        o.w = fmaxf((v.w - m) - tau, 0.f);
        *reinterpret_cast<float4*>(orow + idx) = o;
    }
}

extern "C" void kernel_launch(void* const* d_in, const int* in_sizes, int n_in,
                              void* d_out, int out_size, void* d_ws, size_t ws_size,
                              hipStream_t stream) {
    const float* x = (const float*)d_in[0];
    float* out = (float*)d_out;
    const int rows = out_size / LDIM;  // 16 * 1024 = 16384
    soft_thresh_kernel<<<rows, NT, 0, stream>>>(x, out);
}

// Round 2
// 132.061 us; speedup vs baseline: 1.3754x; 1.3754x over previous
//
#include <hip/hip_runtime.h>
#include <stdint.h>

constexpr int LDIM = 4096;
constexpr int KTOP = 128;
constexpr int WPB  = 4;            // waves (rows) per block
constexpr int NT   = WPB * 64;
constexpr int PT   = LDIM / 64;    // 64 floats per lane
#define EPSF 1e-8f

// order-preserving float<->uint32 key maps (for the bit-space binary search)
__device__ __forceinline__ float key2f(uint32_t k) {
    uint32_t u = (k & 0x80000000u) ? (k & 0x7fffffffu) : ~k;
    return __uint_as_float(u);
}
__device__ __forceinline__ int lane_rank(unsigned long long mask) {
    return __builtin_amdgcn_mbcnt_hi((uint32_t)(mask >> 32),
           __builtin_amdgcn_mbcnt_lo((uint32_t)mask, 0));
}

__global__ __launch_bounds__(NT, 4) void soft_thresh_wave(
        const float* __restrict__ x, float* __restrict__ out) {
    __shared__ float s_top[WPB][KTOP];   // 2 KB total

    const int lane = threadIdx.x & 63;
    const int wid  = threadIdx.x >> 6;
    const size_t base = ((size_t)blockIdx.x * WPB + wid) * LDIM;
    const float* __restrict__ xr = x + base;
    float* __restrict__ orow = out + base;

    // ---- load row: 64 floats/lane in registers, coalesced float4 ----
    float v[PT];
    float vmax = -3.4e38f;
    #pragma unroll
    for (int i = 0; i < PT / 4; ++i) {
        const float4 t = *reinterpret_cast<const float4*>(xr + i * 256 + lane * 4);
        v[i * 4 + 0] = t.x; v[i * 4 + 1] = t.y;
        v[i * 4 + 2] = t.z; v[i * 4 + 3] = t.w;
        vmax = fmaxf(vmax, fmaxf(fmaxf(t.x, t.y), fmaxf(t.z, t.w)));
    }
    #pragma unroll
    for (int off = 32; off > 0; off >>= 1)
        vmax = fmaxf(vmax, __shfl_xor(vmax, off));
    const float m = vmax;                      // row max, same in all lanes

    // ---- binary bit-search for the 128th-largest (ballot counting) ----
    // invariant at end: count(x >= fP) >= 128 > count(x > fP)
    uint32_t P = 0;
    for (int bit = 31; bit >= 0; --bit) {
        const uint32_t cand = P | (1u << bit);
        const float fc = key2f(cand);
        int c = 0;
        #pragma unroll
        for (int i = 0; i < PT; ++i)
            c += __popcll(__ballot(v[i] >= fc));
        if (c >= KTOP) P = cand;
        if (c == KTOP) break;
    }
    const float fP = key2f(P);

    // ---- gather strictly-greater into LDS via ballot rank ----
    int cnt = 0;
    #pragma unroll
    for (int i = 0; i < PT; ++i) {
        const bool pred = v[i] > fP;
        const unsigned long long mask = __ballot(pred);
        const int slot = cnt + lane_rank(mask);
        if (pred && slot < KTOP) s_top[wid][slot] = v[i];
        cnt += __popcll(mask);
    }
    // fill remaining slots with the threshold value (ties)
    for (int s2 = cnt + lane; s2 < KTOP; s2 += 64) s_top[wid][s2] = fP;
    __syncthreads();

    // ---- bitonic sort 128 values descending, 2 per lane ----
    // element e0 at index lane, e1 at index lane+64
    float a0 = s_top[wid][lane];
    float a1 = s_top[wid][lane + 64];
    #pragma unroll
    for (int k = 2; k <= 128; k <<= 1) {
        if (k == 128) {  // j = 64 step: partner is own second register
            const float hi = fmaxf(a0, a1), lo = fminf(a0, a1);
            a0 = hi; a1 = lo;
        }
        #pragma unroll
        for (int j = (k == 128 ? 32 : k >> 1); j >= 1; j >>= 1) {
            {
                const float w = __shfl_xor(a0, j);
                const bool takeMax = ((lane & j) == 0) == ((lane & k) == 0);
                a0 = takeMax ? fmaxf(a0, w) : fminf(a0, w);
            }
            {
                const float w = __shfl_xor(a1, j);
                const int i1 = lane + 64;
                const bool takeMax = ((i1 & j) == 0) == ((i1 & k) == 0);
                a1 = takeMax ? fmaxf(a1, w) : fminf(a1, w);
            }
        }
    }

    // ---- srt = sorted(x) - m ; cumsum via wave shuffle-scan ----
    const float srt0 = a0 - m;
    const float srt1 = a1 - m;
    float c0 = srt0;
    #pragma unroll
    for (int off = 1; off < 64; off <<= 1) {
        const float t = __shfl_up(c0, off);
        if (lane >= off) c0 += t;
    }
    const float tot0 = __shfl(c0, 63);
    float c1 = srt1;
    #pragma unroll
    for (int off = 1; off < 64; off <<= 1) {
        const float t = __shfl_up(c1, off);
        if (lane >= off) c1 += t;
    }
    c1 += tot0;

    // ---- support size + tau (reference formula) ----
    const bool m0 = (float)(lane + 1)  <= c0 / (srt0 + EPSF);
    const bool m1 = (float)(lane + 65) <= c1 / (srt1 + EPSF);
    int support = __popcll(__ballot(m0)) + __popcll(__ballot(m1));
    if (support < 1) support = 1;
    const float cs0 = __shfl(c0, (support - 1) & 63);
    const float cs1 = __shfl(c1, (support - 65) & 63);
    const float csel = (support <= 64) ? cs0 : cs1;
    const float tau = csel / ((float)support + EPSF);

    // ---- output: max((x - m) - tau, 0), coalesced float4 ----
    #pragma unroll
    for (int i = 0; i < PT / 4; ++i) {
        float4 o;
        o.x = fmaxf((v[i * 4 + 0] - m) - tau, 0.f);
        o.y = fmaxf((v[i * 4 + 1] - m) - tau, 0.f);
        o.z = fmaxf((v[i * 4 + 2] - m) - tau, 0.f);
        o.w = fmaxf((v[i * 4 + 3] - m) - tau, 0.f);
        *reinterpret_cast<float4*>(orow + i * 256 + lane * 4) = o;
    }
}

extern "C" void kernel_launch(void* const* d_in, const int* in_sizes, int n_in,
                              void* d_out, int out_size, void* d_ws, size_t ws_size,
                              hipStream_t stream) {
    const float* x = (const float*)d_in[0];
    float* out = (float*)d_out;
    const int rows = out_size / LDIM;          // 16384
    soft_thresh_wave<<<rows / WPB, NT, 0, stream>>>(x, out);
}

// Round 4
// 69.344 us; speedup vs baseline: 2.6194x; 1.9044x over previous
//
#include <hip/hip_runtime.h>
#include <stdint.h>

constexpr int LDIM = 4096;
constexpr int KTOP = 128;
constexpr int WPB  = 4;            // waves (rows) per block
constexpr int NT   = WPB * 64;
constexpr int PT   = LDIM / 64;    // 64 floats per lane
#define EPSF 1e-8f

typedef float floatx4 __attribute__((ext_vector_type(4)));

// order-preserving uint32->float key map (for the rare exact-select fallback)
__device__ __forceinline__ float key2f(uint32_t k) {
    uint32_t u = (k & 0x80000000u) ? (k & 0x7fffffffu) : ~k;
    return __uint_as_float(u);
}
__device__ __forceinline__ int lane_rank(unsigned long long mask) {
    return __builtin_amdgcn_mbcnt_hi((uint32_t)(mask >> 32),
           __builtin_amdgcn_mbcnt_lo((uint32_t)mask, 0));
}

__global__ __launch_bounds__(NT, 4) void soft_thresh_wave(
        const float* __restrict__ x, float* __restrict__ out) {
    __shared__ float s_top[WPB][KTOP];   // used only by the rare fallback

    const int lane = threadIdx.x & 63;
    const int wid  = threadIdx.x >> 6;
    const size_t base = ((size_t)blockIdx.x * WPB + wid) * LDIM;
    const float* __restrict__ xr = x + base;
    float* __restrict__ orow = out + base;

    // ---- load row: 64 floats/lane in registers, coalesced 16B loads ----
    float v[PT];
    #pragma unroll
    for (int i = 0; i < PT / 4; ++i) {
        const floatx4 t = *reinterpret_cast<const floatx4*>(xr + i * 256 + lane * 4);
        v[4 * i] = t.x; v[4 * i + 1] = t.y; v[4 * i + 2] = t.z; v[4 * i + 3] = t.w;
    }

    // ---- row max (4-way ILP tree + wave butterfly) ----
    float m0 = v[0], m1 = v[1], m2 = v[2], m3 = v[3];
    #pragma unroll
    for (int i = 4; i < PT; i += 4) {
        m0 = fmaxf(m0, v[i]);     m1 = fmaxf(m1, v[i + 1]);
        m2 = fmaxf(m2, v[i + 2]); m3 = fmaxf(m3, v[i + 3]);
    }
    float vmax = fmaxf(fmaxf(m0, m1), fmaxf(m2, m3));
    #pragma unroll
    for (int off = 32; off > 0; off >>= 1)
        vmax = fmaxf(vmax, __shfl_xor(vmax, off));
    const float m = vmax;

    // ---- second-distinct-max: degeneracy check for the tau==0 shortcut ----
    const float NINF = -__builtin_inff();
    float s0 = NINF, s1 = NINF, s2 = NINF, s3 = NINF;
    #pragma unroll
    for (int i = 0; i < PT; i += 4) {
        s0 = fmaxf(s0, (v[i]     == m) ? NINF : v[i]);
        s1 = fmaxf(s1, (v[i + 1] == m) ? NINF : v[i + 1]);
        s2 = fmaxf(s2, (v[i + 2] == m) ? NINF : v[i + 2]);
        s3 = fmaxf(s3, (v[i + 3] == m) ? NINF : v[i + 3]);
    }
    float smax = fmaxf(fmaxf(s0, s1), fmaxf(s2, s3));
    #pragma unroll
    for (int off = 32; off > 0; off >>= 1)
        smax = fmaxf(smax, __shfl_xor(smax, off));

    // tau == 0 exactly unless a NON-TIED value lies within 2e-6 of the max:
    // mask[k] needs 0 < |srt[k]| <= (k+1)*1e-8 <= 1.28e-6 to ever be true;
    // all-safe rows provably give mask==false -> support=1 -> tau=0/(1+eps)=0.
    float tau = 0.0f;
    if (__builtin_expect(m - smax < 2e-6f, 0)) {
        // ================= rare exact fallback (round-2 proven path) =======
        // binary bit-search for the 128th-largest: count(>=P)>=128>count(>P)
        uint32_t P = 0;
        for (int bit = 31; bit >= 0; --bit) {
            const uint32_t cand = P | (1u << bit);
            const float fc = key2f(cand);
            int c = 0;
            #pragma unroll
            for (int i = 0; i < PT; ++i) c += __popcll(__ballot(v[i] >= fc));
            if (c >= KTOP) P = cand;
            if (c == KTOP) break;
        }
        const float fP = key2f(P);

        // gather strictly-greater via ballot rank; fill ties with fP
        int cnt = 0;
        #pragma unroll
        for (int i = 0; i < PT; ++i) {
            const bool pred = v[i] > fP;
            const unsigned long long mask = __ballot(pred);
            const int slot = cnt + lane_rank(mask);
            if (pred && slot < KTOP) s_top[wid][slot] = v[i];
            cnt += __popcll(mask);
        }
        for (int q = cnt + lane; q < KTOP; q += 64) s_top[wid][q] = fP;
        // wave-local LDS drain (NOT __syncthreads: branch is wave-uniform only)
        __asm__ __volatile__("s_waitcnt lgkmcnt(0)" ::: "memory");
        float a0 = s_top[wid][lane];
        float a1 = s_top[wid][lane + 64];

        // bitonic sort 128 desc, 2 elems/lane
        #pragma unroll
        for (int k = 2; k <= 128; k <<= 1) {
            if (k == 128) {
                const float hi = fmaxf(a0, a1), lo = fminf(a0, a1);
                a0 = hi; a1 = lo;
            }
            #pragma unroll
            for (int j = (k == 128 ? 32 : k >> 1); j >= 1; j >>= 1) {
                {
                    const float w = __shfl_xor(a0, j);
                    const bool takeMax = ((lane & j) == 0) == ((lane & k) == 0);
                    a0 = takeMax ? fmaxf(a0, w) : fminf(a0, w);
                }
                {
                    const float w = __shfl_xor(a1, j);
                    const int i1 = lane + 64;
                    const bool takeMax = ((i1 & j) == 0) == ((i1 & k) == 0);
                    a1 = takeMax ? fmaxf(a1, w) : fminf(a1, w);
                }
            }
        }

        // srt = sorted - m ; cumsum via wave scan
        const float srt0 = a0 - m;
        const float srt1 = a1 - m;
        float c0 = srt0;
        #pragma unroll
        for (int off = 1; off < 64; off <<= 1) {
            const float t = __shfl_up(c0, off);
            if (lane >= off) c0 += t;
        }
        const float tot0 = __shfl(c0, 63);
        float c1 = srt1;
        #pragma unroll
        for (int off = 1; off < 64; off <<= 1) {
            const float t = __shfl_up(c1, off);
            if (lane >= off) c1 += t;
        }
        c1 += tot0;

        // support + tau (reference formula, f32)
        const bool q0 = (float)(lane + 1)  <= c0 / (srt0 + EPSF);
        const bool q1 = (float)(lane + 65) <= c1 / (srt1 + EPSF);
        int support = __popcll(__ballot(q0)) + __popcll(__ballot(q1));
        if (support < 1) support = 1;
        const float cs0 = __shfl(c0, (support - 1) & 63);
        const float cs1 = __shfl(c1, (support - 65) & 63);
        const float csel = (support <= 64) ? cs0 : cs1;
        tau = csel / ((float)support + EPSF);
        // ===================================================================
    }

    // ---- output: max((x - m) - tau, 0); non-temporal 16B stores ----
    #pragma unroll
    for (int i = 0; i < PT / 4; ++i) {
        floatx4 o;
        o.x = fmaxf((v[4 * i]     - m) - tau, 0.f);
        o.y = fmaxf((v[4 * i + 1] - m) - tau, 0.f);
        o.z = fmaxf((v[4 * i + 2] - m) - tau, 0.f);
        o.w = fmaxf((v[4 * i + 3] - m) - tau, 0.f);
        __builtin_nontemporal_store(o,
            reinterpret_cast<floatx4*>(orow + i * 256 + lane * 4));
    }
}

extern "C" void kernel_launch(void* const* d_in, const int* in_sizes, int n_in,
                              void* d_out, int out_size, void* d_ws, size_t ws_size,
                              hipStream_t stream) {
    const float* x = (const float*)d_in[0];
    float* out = (float*)d_out;
    const int rows = out_size / LDIM;          // 16384
    soft_thresh_wave<<<rows / WPB, NT, 0, stream>>>(x, out);
}